// Round 1
// baseline (285.060 us; speedup 1.0000x reference)
//
#include <hip/hip_runtime.h>
#include <cstdint>
#include <cstddef>

#define N_INST 200
#define HWPIX (448 * 448)        // 200704 pixels per mask
#define W64 3136                 // uint64 words per packed mask
#define SIGMA 2.0f
#define NCHUNK 8                 // K-split factor in pair kernel
#define NTILE 325                // triangular 8x8 tiles over a 25x25 tile grid
#define NPAIR 19900              // 200*199/2 strict upper-triangle pairs

// workspace layout (bytes)
#define P_SLAB  (N_INST * N_INST)              // ints per partial-count slab
#define OFF_P   5017600                        // after packed (200*3136*8)
#define OFF_SP  (OFF_P + NCHUNK * P_SLAB * 4)  // per-chunk per-mask popcounts

// ---------------------------------------------------------------------------
// K1: bitpack with MLP=16. grid (49, 200), 64-thread (1-wave) blocks; thread t
// issues 16 INDEPENDENT lane-contiguous float4 loads (1 KB/wave/instruction)
// and stores one uint64 word. R1 evidence: pack at MLP=1 was latency-bound
// (909 GB/s); MLP=16 is the fix. Fixed pixel permutation (exact for
// AND/popcount): word w = bx*64 + t, bit 4s+q <- pixel bx*4096 + s*256 + t*4 + q.
// ---------------------------------------------------------------------------
__global__ void __launch_bounds__(64)
pack_kernel(const float* __restrict__ seg, uint64_t* __restrict__ packed) {
    const int t = threadIdx.x;                 // 0..63
    const float4* s4 = (const float4*)(seg + (size_t)blockIdx.y * HWPIX
                                           + (size_t)blockIdx.x * 4096);
    float4 v[16];
#pragma unroll
    for (int s = 0; s < 16; ++s) v[s] = s4[s * 64 + t];   // 16 loads in flight
    uint64_t m = 0;
#pragma unroll
    for (int s = 0; s < 16; ++s) {
        uint32_t b = 0;
        b |= (v[s].x > 0.5f) ? 1u : 0u;
        b |= (v[s].y > 0.5f) ? 2u : 0u;
        b |= (v[s].z > 0.5f) ? 4u : 0u;
        b |= (v[s].w > 0.5f) ? 8u : 0u;
        m |= (uint64_t)b << (4 * s);
    }
    packed[(size_t)blockIdx.y * W64 + blockIdx.x * 64 + t] = m;
}

// ---------------------------------------------------------------------------
// K2: pairwise intersection counts, 8x8 tile per wave, K-split by NCHUNK=8.
// 325 tiles x 8 chunks = 2600 waves. Off-diagonal -> P[chunk][j][i];
// diagonal (i==j) -> SP[chunk][i] (per-mask popcounts for free, no atomics).
// Wave-sums <= 7 iters * 64 bits * 64 lanes = 28672 < 2^16: counts packed
// 2-per-int -> 32-reg x 6-step butterfly (exact mod 2^32).
// (R5 config — measured best; R6's K-split 16 was neutral.)
// ---------------------------------------------------------------------------
__global__ void pair_kernel(const uint64_t* __restrict__ packed,
                            int* __restrict__ P,
                            int* __restrict__ SP) {
    const int wt   = blockIdx.x * 4 + (threadIdx.x >> 6);   // 0..2599
    const int lane = threadIdx.x & 63;
    const int t     = wt >> 3;        // tile id 0..324
    const int chunk = wt & 7;

    // decode triangular tile id: t = jt*(jt+1)/2 + it, 0 <= it <= jt <= 24
    int jt = (int)((sqrtf((float)(8 * t + 1)) - 1.0f) * 0.5f);
    while ((jt + 1) * (jt + 2) / 2 <= t) ++jt;
    while (jt * (jt + 1) / 2 > t) --jt;
    const int it = t - jt * (jt + 1) / 2;
    const int i0 = 8 * it, j0 = 8 * jt;

    const int ks = (chunk * 49) >> 3;          // 0,6,12,18,24,30,36,42
    const int ke = ((chunk + 1) * 49) >> 3;    // 6,...,42,49

    const uint64_t* A = packed + (size_t)i0 * W64;
    const uint64_t* B = packed + (size_t)j0 * W64;

    int c[64];
#pragma unroll
    for (int x = 0; x < 64; ++x) c[x] = 0;

    for (int kb = ks; kb < ke; ++kb) {
        const int k = kb * 64 + lane;
        uint64_t a[8], b[8];
#pragma unroll
        for (int r = 0; r < 8; ++r) { a[r] = A[k + r * W64]; b[r] = B[k + r * W64]; }
#pragma unroll
        for (int r = 0; r < 8; ++r)
#pragma unroll
            for (int cc = 0; cc < 8; ++cc)
                c[r * 8 + cc] += __popcll(a[r] & b[cc]);
    }

    int p[32];
#pragma unroll
    for (int m = 0; m < 32; ++m) p[m] = c[2 * m] + (c[2 * m + 1] << 16);
#pragma unroll
    for (int off = 1; off < 64; off <<= 1) {
#pragma unroll
        for (int m = 0; m < 32; ++m) p[m] += __shfl_xor(p[m], off, 64);
    }

    if (lane == 0) {
#pragma unroll
        for (int r = 0; r < 8; ++r) {
#pragma unroll
            for (int cc = 0; cc < 8; ++cc) {
                const int idx = r * 8 + cc;
                const int val = (idx & 1) ? (int)(((unsigned)p[idx >> 1]) >> 16)
                                          : (p[idx >> 1] & 0xFFFF);
                const int i = i0 + r, j = j0 + cc;
                if (i < j)       P[chunk * P_SLAB + j * N_INST + i] = val;
                else if (i == j) SP[chunk * 256 + i] = val;   // popc(a&a)=|mask|
            }
        }
    }
}

// ---------------------------------------------------------------------------
// K3 (fused, R7): single-workgroup epilogue replacing iou_comp + finalize.
// The global sync between "all comp[i] known" and "finalize column j" becomes
// a __syncthreads(): the whole strict-upper-triangle decay matrix (19900
// floats = 79.6 KB) lives in LDS (160 KB/CU on gfx950). Removes one kernel
// node + inter-kernel gap + the 160 KB DTf global round-trip.
// Numerics are op-identical to the previous K3/K4 (same div, same fmax/fmin
// value sets — exact and order-insensitive, same expf) -> absmax stays 0.
// Phase A: Dtri[p] for p = tri(j)+i (coalesced P reads, 8 chunk slabs).
// Phase B: compsq[j] = (max_{i<j} d)^2.
// Phase C: sufmin[j] = min_{i>=j} compsq[i]  (d_ij = 0 for i>=j).
// Phase D: out[j] = scores[j]*exp(SIGMA * min(sufmin[j], min_{i<j}(compsq_i-d^2)))
// ---------------------------------------------------------------------------
__global__ void __launch_bounds__(1024)
epilogue_kernel(const int* __restrict__ P,
                const int* __restrict__ SP,
                const int* __restrict__ labels,
                const float* __restrict__ scores,
                float* __restrict__ out) {
    __shared__ float Dtri[NPAIR];      // 79600 B
    __shared__ int   s_sum[N_INST];
    __shared__ int   s_lab[N_INST];
    __shared__ float compsq[N_INST];
    __shared__ float sufmin[N_INST];
    const int t = threadIdx.x;

    if (t < N_INST) {
        int s = 0;
#pragma unroll
        for (int c = 0; c < NCHUNK; ++c) s += SP[c * 256 + t];
        s_sum[t] = s;
        s_lab[t] = labels[t];
    }
    __syncthreads();

    // Phase A: consecutive threads -> consecutive p -> consecutive i at fixed j
    // => P reads coalesce per chunk slab.
    for (int p = t; p < NPAIR; p += 1024) {
        int j = (int)((sqrtf((float)(8 * p + 1)) + 1.0f) * 0.5f);
        while (j * (j - 1) / 2 > p) --j;
        while ((j + 1) * j / 2 <= p) ++j;
        const int i = p - j * (j - 1) / 2;
        int inter = 0;
#pragma unroll
        for (int c = 0; c < NCHUNK; ++c)
            inter += P[c * P_SLAB + j * N_INST + i];
        const float iou = (float)inter / (float)(s_sum[i] + s_sum[j] - inter);
        Dtri[p] = (s_lab[i] == s_lab[j]) ? iou : 0.0f;
    }
    __syncthreads();

    // Phase B: comp^2 per column (row of Dtri is contiguous: tri(j)..tri(j)+j)
    if (t < N_INST) {
        float m = 0.0f;                        // j=0: empty -> comp 0
        const int base = t * (t - 1) / 2;
        for (int i = 0; i < t; ++i) m = fmaxf(m, Dtri[base + i]);
        compsq[t] = m * m;
    }
    __syncthreads();

    // Phase C: suffix min of compsq (covers all i >= j where d_ij = 0)
    if (t == 0) {
        float s = 3.4e38f;
        for (int k = N_INST - 1; k >= 0; --k) { s = fminf(s, compsq[k]); sufmin[k] = s; }
    }
    __syncthreads();

    // Phase D: finalize
    if (t < N_INST) {
        float mn = sufmin[t];
        const int base = t * (t - 1) / 2;
        for (int i = 0; i < t; ++i) {
            const float d = Dtri[base + i];
            mn = fminf(mn, compsq[i] - d * d);
        }
        out[t] = scores[t] * expf(SIGMA * mn);
    }
}

extern "C" void kernel_launch(void* const* d_in, const int* in_sizes, int n_in,
                              void* d_out, int out_size, void* d_ws, size_t ws_size,
                              hipStream_t stream) {
    const float* seg    = (const float*)d_in[0];   // (200,448,448) fp32 binary
    const float* scores = (const float*)d_in[1];   // (200,) fp32
    const int*   labels = (const int*)d_in[2];     // (200,) int32
    float* out = (float*)d_out;                    // (200,) fp32

    uint64_t* packed = (uint64_t*)d_ws;
    int*      P      = (int*)((char*)d_ws + OFF_P);
    int*      SP     = (int*)((char*)d_ws + OFF_SP);

    {
        dim3 grid(49, N_INST);
        pack_kernel<<<grid, 64, 0, stream>>>(seg, packed);
    }
    pair_kernel<<<NTILE * NCHUNK / 4, 256, 0, stream>>>(packed, P, SP);
    epilogue_kernel<<<1, 1024, 0, stream>>>(P, SP, labels, scores, out);
}

// Round 2
// 252.473 us; speedup vs baseline: 1.1291x; 1.1291x over previous
//
#include <hip/hip_runtime.h>
#include <cstdint>
#include <cstddef>

#define N_INST 200
#define HWPIX (448 * 448)        // 200704 pixels per mask
#define W64 3136                 // uint64 words per packed mask
#define SIGMA 2.0f
#define NCHUNK 8                 // K-split factor in pair kernel
#define NTILE 325                // triangular 8x8 tiles over a 25x25 tile grid

// workspace layout (bytes)
#define P_SLAB  (N_INST * N_INST)              // ints per partial-count slab
#define OFF_P   5017600                        // after packed (200*3136*8)
#define OFF_SP  (OFF_P + NCHUNK * P_SLAB * 4)  // per-chunk per-mask popcounts
#define OFF_CMP (OFF_SP + NCHUNK * 256 * 4)    // comp[200] fp32

// ---------------------------------------------------------------------------
// K1: bitpack with MLP=16. grid (49, 200), 64-thread (1-wave) blocks; thread t
// issues 16 INDEPENDENT lane-contiguous float4 loads (1 KB/wave/instruction)
// and stores one uint64 word. R1 evidence: pack at MLP=1 was latency-bound
// (909 GB/s); MLP=16 is the fix. Fixed pixel permutation (exact for
// AND/popcount): word w = bx*64 + t, bit 4s+q <- pixel bx*4096 + s*256 + t*4 + q.
// ---------------------------------------------------------------------------
__global__ void __launch_bounds__(64)
pack_kernel(const float* __restrict__ seg, uint64_t* __restrict__ packed) {
    const int t = threadIdx.x;                 // 0..63
    const float4* s4 = (const float4*)(seg + (size_t)blockIdx.y * HWPIX
                                           + (size_t)blockIdx.x * 4096);
    float4 v[16];
#pragma unroll
    for (int s = 0; s < 16; ++s) v[s] = s4[s * 64 + t];   // 16 loads in flight
    uint64_t m = 0;
#pragma unroll
    for (int s = 0; s < 16; ++s) {
        uint32_t b = 0;
        b |= (v[s].x > 0.5f) ? 1u : 0u;
        b |= (v[s].y > 0.5f) ? 2u : 0u;
        b |= (v[s].z > 0.5f) ? 4u : 0u;
        b |= (v[s].w > 0.5f) ? 8u : 0u;
        m |= (uint64_t)b << (4 * s);
    }
    packed[(size_t)blockIdx.y * W64 + blockIdx.x * 64 + t] = m;
}

// ---------------------------------------------------------------------------
// K2: pairwise intersection counts, 8x8 tile per wave, K-split by NCHUNK=8.
// 325 tiles x 8 chunks = 2600 waves. Off-diagonal -> P[chunk][j][i];
// diagonal (i==j) -> SP[chunk][i] (per-mask popcounts for free, no atomics).
// Wave-sums <= 7 iters * 64 bits * 64 lanes = 28672 < 2^16: counts packed
// 2-per-int -> 32-reg x 6-step butterfly (exact mod 2^32).
// (R5 config — measured best; R6's K-split 16 was neutral.)
// ---------------------------------------------------------------------------
__global__ void pair_kernel(const uint64_t* __restrict__ packed,
                            int* __restrict__ P,
                            int* __restrict__ SP) {
    const int wt   = blockIdx.x * 4 + (threadIdx.x >> 6);   // 0..2599
    const int lane = threadIdx.x & 63;
    const int t     = wt >> 3;        // tile id 0..324
    const int chunk = wt & 7;

    // decode triangular tile id: t = jt*(jt+1)/2 + it, 0 <= it <= jt <= 24
    int jt = (int)((sqrtf((float)(8 * t + 1)) - 1.0f) * 0.5f);
    while ((jt + 1) * (jt + 2) / 2 <= t) ++jt;
    while (jt * (jt + 1) / 2 > t) --jt;
    const int it = t - jt * (jt + 1) / 2;
    const int i0 = 8 * it, j0 = 8 * jt;

    const int ks = (chunk * 49) >> 3;          // 0,6,12,18,24,30,36,42
    const int ke = ((chunk + 1) * 49) >> 3;    // 6,...,42,49

    const uint64_t* A = packed + (size_t)i0 * W64;
    const uint64_t* B = packed + (size_t)j0 * W64;

    int c[64];
#pragma unroll
    for (int x = 0; x < 64; ++x) c[x] = 0;

    for (int kb = ks; kb < ke; ++kb) {
        const int k = kb * 64 + lane;
        uint64_t a[8], b[8];
#pragma unroll
        for (int r = 0; r < 8; ++r) { a[r] = A[k + r * W64]; b[r] = B[k + r * W64]; }
#pragma unroll
        for (int r = 0; r < 8; ++r)
#pragma unroll
            for (int cc = 0; cc < 8; ++cc)
                c[r * 8 + cc] += __popcll(a[r] & b[cc]);
    }

    int p[32];
#pragma unroll
    for (int m = 0; m < 32; ++m) p[m] = c[2 * m] + (c[2 * m + 1] << 16);
#pragma unroll
    for (int off = 1; off < 64; off <<= 1) {
#pragma unroll
        for (int m = 0; m < 32; ++m) p[m] += __shfl_xor(p[m], off, 64);
    }

    if (lane == 0) {
#pragma unroll
        for (int r = 0; r < 8; ++r) {
#pragma unroll
            for (int cc = 0; cc < 8; ++cc) {
                const int idx = r * 8 + cc;
                const int val = (idx & 1) ? (int)(((unsigned)p[idx >> 1]) >> 16)
                                          : (p[idx >> 1] & 0xFFFF);
                const int i = i0 + r, j = j0 + cc;
                if (i < j)       P[chunk * P_SLAB + j * N_INST + i] = val;
                else if (i == j) SP[chunk * 256 + i] = val;   // popc(a&a)=|mask|
            }
        }
    }
}

// ---------------------------------------------------------------------------
// K3: reduce chunk partials -> decay_iou[i][j] (i<j) for column j, fused with
// comp[j] = max_{i<j} decay_iou[i][j]. Block j writes the DTf row for K4 AND
// reduces the max in the same pass. 200 parallel blocks — keeps the
// remote-dirty-L2 reads spread across the whole chip (R7 lesson: one CU
// pulling these lines is latency-throttled, +34 us).
// ---------------------------------------------------------------------------
#define OFF_DT  (OFF_CMP + 1024)               // DTf[j*200+i] fp32, i<j only

__global__ void iou_comp_kernel(const int* __restrict__ P,
                                const int* __restrict__ SP,
                                const int* __restrict__ labels,
                                float* __restrict__ DTf,
                                float* __restrict__ comp) {
    const int j = blockIdx.x;
    const int t = threadIdx.x;
    int sj = 0;
#pragma unroll
    for (int cch = 0; cch < NCHUNK; ++cch) sj += SP[cch * 256 + j];
    const int lj = labels[j];
    float m = 0.0f;                            // j=0: empty column -> comp 0
    for (int i = t; i < j; i += 64) {
        int inter = 0;
#pragma unroll
        for (int cch = 0; cch < NCHUNK; ++cch)
            inter += P[cch * P_SLAB + j * N_INST + i];
        int si = 0;
#pragma unroll
        for (int cch = 0; cch < NCHUNK; ++cch) si += SP[cch * 256 + i];
        const float iou = (float)inter / (float)(si + sj - inter);
        const float d = (labels[i] == lj) ? iou : 0.0f;
        DTf[j * N_INST + i] = d;
        m = fmaxf(m, d);
    }
#pragma unroll
    for (int off = 1; off < 64; off <<= 1) m = fmaxf(m, __shfl_xor(m, off, 64));
    if (t == 0) comp[j] = m;
}

// ---------------------------------------------------------------------------
// K4: out[j] = scores[j] * exp(SIGMA * min_i(comp[i]^2 - d_ij^2)),
//     d_ij = decay_iou[i][j] = (i<j ? DTf[j*200+i] : 0).
// (min of exp == exp of min; exp monotone.) Coalesced row reads, L2-hot.
// ---------------------------------------------------------------------------
__global__ void finalize_kernel(const float* __restrict__ DTf,
                                const float* __restrict__ comp,
                                const float* __restrict__ scores,
                                float* __restrict__ out) {
    const int j = blockIdx.x;
    const int t = threadIdx.x;
    const float* row = DTf + (size_t)j * N_INST;
    float mn = 3.4e38f;
    for (int i = t; i < N_INST; i += 64) {
        const float ci = comp[i];
        float v = ci * ci;
        if (i < j) { const float d = row[i]; v -= d * d; }
        mn = fminf(mn, v);
    }
#pragma unroll
    for (int off = 1; off < 64; off <<= 1) mn = fminf(mn, __shfl_xor(mn, off, 64));
    if (t == 0) out[j] = scores[j] * expf(SIGMA * mn);
}

extern "C" void kernel_launch(void* const* d_in, const int* in_sizes, int n_in,
                              void* d_out, int out_size, void* d_ws, size_t ws_size,
                              hipStream_t stream) {
    const float* seg    = (const float*)d_in[0];   // (200,448,448) fp32 binary
    const float* scores = (const float*)d_in[1];   // (200,) fp32
    const int*   labels = (const int*)d_in[2];     // (200,) int32
    float* out = (float*)d_out;                    // (200,) fp32

    uint64_t* packed = (uint64_t*)d_ws;
    int*      P      = (int*)((char*)d_ws + OFF_P);
    int*      SP     = (int*)((char*)d_ws + OFF_SP);
    float*    comp   = (float*)((char*)d_ws + OFF_CMP);
    float*    DTf    = (float*)((char*)d_ws + OFF_DT);

    {
        dim3 grid(49, N_INST);
        pack_kernel<<<grid, 64, 0, stream>>>(seg, packed);
    }
    pair_kernel<<<NTILE * NCHUNK / 4, 256, 0, stream>>>(packed, P, SP);
    iou_comp_kernel<<<N_INST, 64, 0, stream>>>(P, SP, labels, DTf, comp);
    finalize_kernel<<<N_INST, 64, 0, stream>>>(DTf, comp, scores, out);
}